// Round 12
// baseline (403.104 us; speedup 1.0000x reference)
//
#include <hip/hip_runtime.h>
#include <hip/hip_bf16.h>

typedef short bf16x8 __attribute__((ext_vector_type(8)));
typedef float f32x4 __attribute__((ext_vector_type(4)));
typedef float f4    __attribute__((ext_vector_type(4)));
typedef unsigned short u16;

#define D_DIM  128
#define S_LEN  16384
#define NBLK   1024      // 4 blocks/CU
#define NTILES 4096      // 262144 rows / 64 rows per block-tile (4 waves x 16 rows)
#define ITERS  4         // NTILES / NBLK

__device__ __forceinline__ u16 f2bf(float f) {
    __hip_bfloat16 h = __float2bfloat16(f);
    return __builtin_bit_cast(u16, h);
}

__device__ __forceinline__ float bf2f(u16 b) {
    unsigned u = ((unsigned)b) << 16;
    return __builtin_bit_cast(float, u);
}

// ---- prep: convert W1,W2 (f32) to bf16 MFMA B-fragment layout in d_ws ----
// frag(L,kc,ct), lane l=(g=l>>4, ln=l&15), j=0..7:
//   element W_L[kc*32 + g*8 + j][(ct>>2)*64 + (ct&3) + 4*ln]
// flat u16 index: (((L*4+kc)*8+ct)*64 + l)*8 + j
__global__ void __launch_bounds__(256)
prep_weights(const float* __restrict__ W1, const float* __restrict__ W2,
             u16* __restrict__ wf) {
    const int t  = blockIdx.x * 256 + threadIdx.x;   // 0..4095
    const int L  = t >> 11;
    const int kc = (t >> 9) & 3;
    const int ct = (t >> 6) & 7;
    const int l  = t & 63;
    const float* W = L ? W2 : W1;
    const int col = (ct >> 2) * 64 + (ct & 3) + 4 * (l & 15);
    const int k0  = kc * 32 + (l >> 4) * 8;
    bf16x8 frag;
#pragma unroll
    for (int j = 0; j < 8; ++j)
        frag[j] = (short)f2bf(W[(k0 + j) * 128 + col]);
    *(bf16x8*)&wf[(size_t)t * 8] = frag;
}

struct Pre {
    f4    xv[8];    // wave's 16x128 x-tile fragment slice (32 VGPR)
    float mfac[8];  // mask * decay factor for readback rows (8 VGPR)
};

__device__ __forceinline__ void prefetch_issue(const float* __restrict__ x,
                                               const int* __restrict__ mask,
                                               int tile, int wv, int l, int ln, int g,
                                               Pre& p) {
    const int row0 = tile * 64 + wv * 16;
    const float* xp = x + (long)(row0 + ln) * D_DIM + g * 8;
#pragma unroll
    for (int kc = 0; kc < 4; ++kc) {
        p.xv[2*kc]   = *(const f4*)(xp + kc*32);
        p.xv[2*kc+1] = *(const f4*)(xp + kc*32 + 4);
    }
#pragma unroll
    for (int i = 0; i < 8; ++i) {
        const int fr = row0 + 2*i + (l >> 5);
        const unsigned s = (unsigned)(fr & (S_LEN - 1));
        const float sc = (((s + 1u) % 10u) == 0u) ? 0.1f : 1.0f;
        p.mfac[i] = mask[fr] ? sc : 0.0f;
    }
}

__device__ __forceinline__ void compute_tile(int tile, const Pre& p,
    const u16* __restrict__ w1f, const u16* __restrict__ w2f, u16* __restrict__ hw,
    const float* b1f, const float* b2f,
    float* __restrict__ out, int wv, int l, int ln, int g) {

    const int row0 = tile * 64 + wv * 16;
    const f32x4 zero = {0.f, 0.f, 0.f, 0.f};

    // ---- convert prefetched x to bf16 A-fragments ----
    bf16x8 a[4];
#pragma unroll
    for (int kc = 0; kc < 4; ++kc) {
        const f4 lo = p.xv[2*kc], hi = p.xv[2*kc+1];
        bf16x8 t;
        t[0]=(short)f2bf(lo[0]); t[1]=(short)f2bf(lo[1]); t[2]=(short)f2bf(lo[2]); t[3]=(short)f2bf(lo[3]);
        t[4]=(short)f2bf(hi[0]); t[5]=(short)f2bf(hi[1]); t[6]=(short)f2bf(hi[2]); t[7]=(short)f2bf(hi[3]);
        a[kc] = t;
    }

    // ---- layer 1: H = X @ W1 — B-frags from global frag array (L1/L2-hot, coalesced 1KB) ----
    f32x4 acc1[8];
#pragma unroll
    for (int ct = 0; ct < 8; ++ct) acc1[ct] = zero;
#pragma unroll
    for (int kc = 0; kc < 4; ++kc) {
#pragma unroll
        for (int ct = 0; ct < 8; ++ct) {
            const bf16x8 b = *(const bf16x8*)&w1f[(size_t)((kc*8 + ct)*64 + l) * 8];
            acc1[ct] = __builtin_amdgcn_mfma_f32_16x16x32_bf16(a[kc], b, acc1[ct], 0, 0, 0);
        }
    }

    // ---- bias + silu -> h to per-wave LDS (swizzled, true-column layout) ----
#pragma unroll
    for (int hh = 0; hh < 2; ++hh) {
#pragma unroll
        for (int r = 0; r < 4; ++r) {
            const int row = g*4 + r;
            float z0 = acc1[hh*4+0][r] + b1f[hh*4+0];
            float z1 = acc1[hh*4+1][r] + b1f[hh*4+1];
            float z2 = acc1[hh*4+2][r] + b1f[hh*4+2];
            float z3 = acc1[hh*4+3][r] + b1f[hh*4+3];
            ushort4 pk;
            pk.x = f2bf(z0 / (1.f + __expf(-z0)));
            pk.y = f2bf(z1 / (1.f + __expf(-z1)));
            pk.z = f2bf(z2 / (1.f + __expf(-z2)));
            pk.w = f2bf(z3 / (1.f + __expf(-z3)));
            const int c0  = hh*64 + 4*ln;
            const int idx = row*128 + (((c0 >> 3) ^ (row & 7)) << 3) + (c0 & 7);
            *(ushort4*)&hw[idx] = pk;
        }
    }

    // ---- read h A-fragments (same-wave LDS round trip, no barrier) ----
    bf16x8 ha[4];
#pragma unroll
    for (int kc = 0; kc < 4; ++kc) {
        const int u = kc*4 + g;
        ha[kc] = *(const bf16x8*)&hw[ln*128 + ((u ^ (ln & 7)) << 3)];
    }

    // ---- layer 2: Y = H @ W2 — B-frags from global frag array ----
    f32x4 acc2[8];
#pragma unroll
    for (int ct = 0; ct < 8; ++ct) acc2[ct] = zero;
#pragma unroll
    for (int kc = 0; kc < 4; ++kc) {
#pragma unroll
        for (int ct = 0; ct < 8; ++ct) {
            const bf16x8 b = *(const bf16x8*)&w2f[(size_t)((kc*8 + ct)*64 + l) * 8];
            acc2[ct] = __builtin_amdgcn_mfma_f32_16x16x32_bf16(ha[kc], b, acc2[ct], 0, 0, 0);
        }
    }

    // ---- Y (+bias) -> bf16 back into the SAME per-wave buffer ----
#pragma unroll
    for (int hh = 0; hh < 2; ++hh) {
#pragma unroll
        for (int r = 0; r < 4; ++r) {
            const int row = g*4 + r;
            ushort4 pk;
            pk.x = f2bf(acc2[hh*4+0][r] + b2f[hh*4+0]);
            pk.y = f2bf(acc2[hh*4+1][r] + b2f[hh*4+1]);
            pk.z = f2bf(acc2[hh*4+2][r] + b2f[hh*4+2]);
            pk.w = f2bf(acc2[hh*4+3][r] + b2f[hh*4+3]);
            const int c0  = hh*64 + 4*ln;
            const int idx = row*128 + (((c0 >> 3) ^ (row & 7)) << 3) + (c0 & 7);
            *(ushort4*)&hw[idx] = pk;
        }
    }

    // ---- linear readback + mask/decay + lane-contiguous 1 KiB NONTEMPORAL stores ----
#pragma unroll
    for (int i = 0; i < 8; ++i) {
        const int row = 2*i + (l >> 5);
        const int c0  = 4 * (l & 31);
        const int u   = c0 >> 3;
        const int idx = row*128 + ((u ^ (row & 7)) << 3) + (c0 & 7);
        const ushort4 pk = *(const ushort4*)&hw[idx];
        f4 f;
        f[0] = bf2f(pk.x) * p.mfac[i];
        f[1] = bf2f(pk.y) * p.mfac[i];
        f[2] = bf2f(pk.z) * p.mfac[i];
        f[3] = bf2f(pk.w) * p.mfac[i];
        __builtin_nontemporal_store(f, (f4*)(out + (long)(row0 + row) * D_DIM + c0));
    }
}

__global__ void __launch_bounds__(256, 4)
ssm_fused_v12(const float* __restrict__ x,
              const int*   __restrict__ mask,
              const u16*   __restrict__ wf,
              const float* __restrict__ b1,
              const float* __restrict__ b2,
              float* __restrict__ out) {
    // LDS: per-wave h/y buffer only -> 16 KiB/block -> 4 blocks/CU, 16 waves/CU (4/SIMD)
    __shared__ __align__(16) u16 hlds[4*16*128];

    const int tid = threadIdx.x;
    const int l   = tid & 63;
    const int ln  = tid & 15;
    const int g   = (tid >> 4) & 3;
    const int wv  = tid >> 6;

    const u16* w1f = wf;
    const u16* w2f = wf + 16384;   // 32 frags * 64 lanes * 8 u16

    // per-lane bias fragments at permuted columns
    float b1f[8], b2f[8];
#pragma unroll
    for (int ct = 0; ct < 8; ++ct) {
        const int col = (ct >> 2)*64 + (ct & 3) + 4*ln;
        b1f[ct] = b1[col];
        b2f[ct] = b2[col];
    }

    u16* hw = hlds + wv * 2048;

    // ---- software-pipelined main loop (ping-pong Pre, pinned issue points) ----
    Pre pa, pb;
    prefetch_issue(x, mask, blockIdx.x, wv, l, ln, g, pa);
    __builtin_amdgcn_sched_barrier(0);

#pragma unroll 1
    for (int itp = 0; itp < ITERS/2; ++itp) {
        const int tA = blockIdx.x + (2*itp) * NBLK;
        const int tB = tA + NBLK;
        int tC = tB + NBLK; if (tC >= NTILES) tC = tB;

        prefetch_issue(x, mask, tB, wv, l, ln, g, pb);
        __builtin_amdgcn_sched_barrier(0);
        compute_tile(tA, pa, w1f, w2f, hw, b1f, b2f, out, wv, l, ln, g);

        prefetch_issue(x, mask, tC, wv, l, ln, g, pa);
        __builtin_amdgcn_sched_barrier(0);
        compute_tile(tB, pb, w1f, w2f, hw, b1f, b2f, out, wv, l, ln, g);
    }
}

extern "C" void kernel_launch(void* const* d_in, const int* in_sizes, int n_in,
                              void* d_out, int out_size, void* d_ws, size_t ws_size,
                              hipStream_t stream) {
    const float* x    = (const float*)d_in[0];
    const int*   mask = (const int*)d_in[1];
    const float* W1   = (const float*)d_in[2];
    const float* b1   = (const float*)d_in[3];
    const float* W2   = (const float*)d_in[4];
    const float* b2   = (const float*)d_in[5];
    float* out = (float*)d_out;
    u16*   wf  = (u16*)d_ws;   // 64 KiB used

    hipLaunchKernelGGL(prep_weights, dim3(16), dim3(256), 0, stream, W1, W2, wf);
    hipLaunchKernelGGL(ssm_fused_v12, dim3(NBLK), dim3(256), 0, stream,
                       x, mask, wf, b1, b2, out);
}

// Round 13
// 250.320 us; speedup vs baseline: 1.6104x; 1.6104x over previous
//
#include <hip/hip_runtime.h>
#include <hip/hip_bf16.h>

typedef short bf16x8 __attribute__((ext_vector_type(8)));
typedef float f32x4 __attribute__((ext_vector_type(4)));
typedef float f4    __attribute__((ext_vector_type(4)));
typedef unsigned short u16;

#define D_DIM  128
#define S_LEN  16384
#define NBLK   1024      // 4 blocks/CU when VGPR<=128
#define NTILES 4096      // 262144 rows / 64 rows per block-tile (4 waves x 16 rows)
#define ITERS  4         // NTILES / NBLK

__device__ __forceinline__ u16 f2bf(float f) {
    __hip_bfloat16 h = __float2bfloat16(f);
    return __builtin_bit_cast(u16, h);
}

__device__ __forceinline__ float bf2f(u16 b) {
    unsigned u = ((unsigned)b) << 16;
    return __builtin_bit_cast(float, u);
}

// ---- prep: convert W1,W2 (f32) to bf16 MFMA B-fragment layout in d_ws ----
// frag(L,kc,ct), lane l=(g=l>>4, ln=l&15), j=0..7:
//   element W_L[kc*32 + g*8 + j][(ct>>2)*64 + (ct&3) + 4*ln]
// flat u16 index: (((L*4+kc)*8+ct)*64 + l)*8 + j     [verified R12: absmax ok]
__global__ void __launch_bounds__(256)
prep_weights(const float* __restrict__ W1, const float* __restrict__ W2,
             u16* __restrict__ wf) {
    const int t  = blockIdx.x * 256 + threadIdx.x;   // 0..4095
    const int L  = t >> 11;
    const int kc = (t >> 9) & 3;
    const int ct = (t >> 6) & 7;
    const int l  = t & 63;
    const float* W = L ? W2 : W1;
    const int col = (ct >> 2) * 64 + (ct & 3) + 4 * (l & 15);
    const int k0  = kc * 32 + (l >> 4) * 8;
    bf16x8 frag;
#pragma unroll
    for (int j = 0; j < 8; ++j)
        frag[j] = (short)f2bf(W[(k0 + j) * 128 + col]);
    *(bf16x8*)&wf[(size_t)t * 8] = frag;
}

struct Pre {
    f4    xv[8];    // wave's 16x128 x-tile fragment slice (32 VGPR)
    float mfac[8];  // mask * decay factor for readback rows (8 VGPR)
};

__device__ __forceinline__ void prefetch_issue(const float* __restrict__ x,
                                               const int* __restrict__ mask,
                                               int tile, int wv, int l, int ln, int g,
                                               Pre& p) {
    const int row0 = tile * 64 + wv * 16;
    const float* xp = x + (long)(row0 + ln) * D_DIM + g * 8;
#pragma unroll
    for (int kc = 0; kc < 4; ++kc) {
        p.xv[2*kc]   = *(const f4*)(xp + kc*32);
        p.xv[2*kc+1] = *(const f4*)(xp + kc*32 + 4);
    }
#pragma unroll
    for (int i = 0; i < 8; ++i) {
        const int fr = row0 + 2*i + (l >> 5);
        const unsigned s = (unsigned)(fr & (S_LEN - 1));
        const float sc = (((s + 1u) % 10u) == 0u) ? 0.1f : 1.0f;
        p.mfac[i] = mask[fr] ? sc : 0.0f;
    }
}

// compute tile `tile` from p; mid-tile, issue prefetch of tile `ptile` into pn.
// Prefetch sits AFTER layer-1's weight-frag uses and BEFORE layer-2's weight
// loads, so no weight vmcnt-wait ever drains the x stream (in-order vmcnt).
__device__ __forceinline__ void compute_tile(int tile, const Pre& p,
    int ptile, Pre& pn,
    const float* __restrict__ x, const int* __restrict__ mask,
    const u16* __restrict__ w1f, const u16* __restrict__ w2f, u16* __restrict__ hw,
    const float* b1f, const float* b2f,
    float* __restrict__ out, int wv, int l, int ln, int g) {

    const int row0 = tile * 64 + wv * 16;
    const f32x4 zero = {0.f, 0.f, 0.f, 0.f};

    // ---- convert prefetched x to bf16 A-fragments (drains x vmcnt here) ----
    bf16x8 a[4];
#pragma unroll
    for (int kc = 0; kc < 4; ++kc) {
        const f4 lo = p.xv[2*kc], hi = p.xv[2*kc+1];
        bf16x8 t;
        t[0]=(short)f2bf(lo[0]); t[1]=(short)f2bf(lo[1]); t[2]=(short)f2bf(lo[2]); t[3]=(short)f2bf(lo[3]);
        t[4]=(short)f2bf(hi[0]); t[5]=(short)f2bf(hi[1]); t[6]=(short)f2bf(hi[2]); t[7]=(short)f2bf(hi[3]);
        a[kc] = t;
    }

    // ---- layer 1: H = X @ W1 — B-frags from global frag array (L2-hot, 1KB/instr) ----
    f32x4 acc1[8];
#pragma unroll
    for (int ct = 0; ct < 8; ++ct) acc1[ct] = zero;
#pragma unroll
    for (int kc = 0; kc < 4; ++kc) {
#pragma unroll
        for (int ct = 0; ct < 8; ++ct) {
            const bf16x8 b = *(const bf16x8*)&w1f[(size_t)((kc*8 + ct)*64 + l) * 8];
            acc1[ct] = __builtin_amdgcn_mfma_f32_16x16x32_bf16(a[kc], b, acc1[ct], 0, 0, 0);
        }
    }

    // ---- bias + silu -> h to per-wave LDS (swizzled, true-column layout) ----
#pragma unroll
    for (int hh = 0; hh < 2; ++hh) {
#pragma unroll
        for (int r = 0; r < 4; ++r) {
            const int row = g*4 + r;
            float z0 = acc1[hh*4+0][r] + b1f[hh*4+0];
            float z1 = acc1[hh*4+1][r] + b1f[hh*4+1];
            float z2 = acc1[hh*4+2][r] + b1f[hh*4+2];
            float z3 = acc1[hh*4+3][r] + b1f[hh*4+3];
            ushort4 pk;
            pk.x = f2bf(z0 / (1.f + __expf(-z0)));
            pk.y = f2bf(z1 / (1.f + __expf(-z1)));
            pk.z = f2bf(z2 / (1.f + __expf(-z2)));
            pk.w = f2bf(z3 / (1.f + __expf(-z3)));
            const int c0  = hh*64 + 4*ln;
            const int idx = row*128 + (((c0 >> 3) ^ (row & 7)) << 3) + (c0 & 7);
            *(ushort4*)&hw[idx] = pk;
        }
    }

    // ---- MID-TILE PREFETCH: x/mask for tile `ptile` (HBM latency hides under
    //      L2 compute + epilogue + next tile's start; W2 waits won't drain it) ----
    prefetch_issue(x, mask, ptile, wv, l, ln, g, pn);
    __builtin_amdgcn_sched_barrier(0);

    // ---- read h A-fragments (same-wave LDS round trip, no barrier) ----
    bf16x8 ha[4];
#pragma unroll
    for (int kc = 0; kc < 4; ++kc) {
        const int u = kc*4 + g;
        ha[kc] = *(const bf16x8*)&hw[ln*128 + ((u ^ (ln & 7)) << 3)];
    }

    // ---- layer 2: Y = H @ W2 — B-frags from global frag array ----
    f32x4 acc2[8];
#pragma unroll
    for (int ct = 0; ct < 8; ++ct) acc2[ct] = zero;
#pragma unroll
    for (int kc = 0; kc < 4; ++kc) {
#pragma unroll
        for (int ct = 0; ct < 8; ++ct) {
            const bf16x8 b = *(const bf16x8*)&w2f[(size_t)((kc*8 + ct)*64 + l) * 8];
            acc2[ct] = __builtin_amdgcn_mfma_f32_16x16x32_bf16(ha[kc], b, acc2[ct], 0, 0, 0);
        }
    }

    // ---- Y (+bias) -> bf16 back into the SAME per-wave buffer ----
#pragma unroll
    for (int hh = 0; hh < 2; ++hh) {
#pragma unroll
        for (int r = 0; r < 4; ++r) {
            const int row = g*4 + r;
            ushort4 pk;
            pk.x = f2bf(acc2[hh*4+0][r] + b2f[hh*4+0]);
            pk.y = f2bf(acc2[hh*4+1][r] + b2f[hh*4+1]);
            pk.z = f2bf(acc2[hh*4+2][r] + b2f[hh*4+2]);
            pk.w = f2bf(acc2[hh*4+3][r] + b2f[hh*4+3]);
            const int c0  = hh*64 + 4*ln;
            const int idx = row*128 + (((c0 >> 3) ^ (row & 7)) << 3) + (c0 & 7);
            *(ushort4*)&hw[idx] = pk;
        }
    }

    // ---- linear readback + mask/decay + lane-contiguous 1 KiB NONTEMPORAL stores ----
#pragma unroll
    for (int i = 0; i < 8; ++i) {
        const int row = 2*i + (l >> 5);
        const int c0  = 4 * (l & 31);
        const int u   = c0 >> 3;
        const int idx = row*128 + ((u ^ (row & 7)) << 3) + (c0 & 7);
        const ushort4 pk = *(const ushort4*)&hw[idx];
        f4 f;
        f[0] = bf2f(pk.x) * p.mfac[i];
        f[1] = bf2f(pk.y) * p.mfac[i];
        f[2] = bf2f(pk.z) * p.mfac[i];
        f[3] = bf2f(pk.w) * p.mfac[i];
        __builtin_nontemporal_store(f, (f4*)(out + (long)(row0 + row) * D_DIM + c0));
    }
}

__global__ void __launch_bounds__(256, 2)
ssm_fused_v13(const float* __restrict__ x,
              const int*   __restrict__ mask,
              const u16*   __restrict__ wf,
              const float* __restrict__ b1,
              const float* __restrict__ b2,
              float* __restrict__ out) {
    // LDS: per-wave h/y buffer only -> 16 KiB/block; occupancy VGPR-limited (~4 blocks/CU)
    __shared__ __align__(16) u16 hlds[4*16*128];

    const int tid = threadIdx.x;
    const int l   = tid & 63;
    const int ln  = tid & 15;
    const int g   = (tid >> 4) & 3;
    const int wv  = tid >> 6;

    const u16* w1f = wf;
    const u16* w2f = wf + 16384;   // 32 frags * 64 lanes * 8 u16

    // per-lane bias fragments at permuted columns
    float b1f[8], b2f[8];
#pragma unroll
    for (int ct = 0; ct < 8; ++ct) {
        const int col = (ct >> 2)*64 + (ct & 3) + 4*ln;
        b1f[ct] = b1[col];
        b2f[ct] = b2[col];
    }

    u16* hw = hlds + wv * 2048;

    // ---- software-pipelined main loop (ping-pong Pre, mid-tile pinned prefetch) ----
    Pre pa, pb;
    prefetch_issue(x, mask, blockIdx.x, wv, l, ln, g, pa);
    __builtin_amdgcn_sched_barrier(0);

#pragma unroll 1
    for (int itp = 0; itp < ITERS/2; ++itp) {
        const int tA = blockIdx.x + (2*itp) * NBLK;
        const int tB = tA + NBLK;
        int tC = tB + NBLK; if (tC >= NTILES) tC = tB;

        compute_tile(tA, pa, tB, pb, x, mask, w1f, w2f, hw, b1f, b2f, out, wv, l, ln, g);
        compute_tile(tB, pb, tC, pa, x, mask, w1f, w2f, hw, b1f, b2f, out, wv, l, ln, g);
    }
}

extern "C" void kernel_launch(void* const* d_in, const int* in_sizes, int n_in,
                              void* d_out, int out_size, void* d_ws, size_t ws_size,
                              hipStream_t stream) {
    const float* x    = (const float*)d_in[0];
    const int*   mask = (const int*)d_in[1];
    const float* W1   = (const float*)d_in[2];
    const float* b1   = (const float*)d_in[3];
    const float* W2   = (const float*)d_in[4];
    const float* b2   = (const float*)d_in[5];
    float* out = (float*)d_out;
    u16*   wf  = (u16*)d_ws;   // 64 KiB used

    hipLaunchKernelGGL(prep_weights, dim3(16), dim3(256), 0, stream, W1, W2, wf);
    hipLaunchKernelGGL(ssm_fused_v13, dim3(NBLK), dim3(256), 0, stream,
                       x, mask, wf, b1, b2, out);
}

// Round 14
// 132.758 us; speedup vs baseline: 3.0364x; 1.8855x over previous
//
#include <hip/hip_runtime.h>
#include <hip/hip_bf16.h>

typedef short bf16x8 __attribute__((ext_vector_type(8)));
typedef float f32x4 __attribute__((ext_vector_type(4)));
typedef float f4    __attribute__((ext_vector_type(4)));
typedef unsigned short u16;

#define D_DIM  128
#define S_LEN  16384
#define NBLK   512
#define NTILES 4096      // 262144 rows / 64 rows per block-tile (4 waves x 16 rows)
#define ITERS  8         // NTILES / NBLK

__device__ __forceinline__ u16 f2bf(float f) {
    __hip_bfloat16 h = __float2bfloat16(f);
    return __builtin_bit_cast(u16, h);
}

__device__ __forceinline__ float bf2f(u16 b) {
    unsigned u = ((unsigned)b) << 16;
    return __builtin_bit_cast(float, u);
}

// ---- prep: W2 (f32) -> bf16 MFMA B-fragment layout in d_ws ----
// frag(kc,ct), lane l=(g=l>>4, ln=l&15), j=0..7:
//   element W2[kc*32 + g*8 + j][(ct>>2)*64 + (ct&3) + 4*ln]
// flat u16 index: ((kc*8+ct)*64 + l)*8 + j      [layout verified R12/R13]
__global__ void __launch_bounds__(256)
prep_w2(const float* __restrict__ W2, u16* __restrict__ wf) {
    const int t  = blockIdx.x * 256 + threadIdx.x;   // 0..2047
    const int kc = (t >> 9) & 3;
    const int ct = (t >> 6) & 7;
    const int l  = t & 63;
    const int col = (ct >> 2) * 64 + (ct & 3) + 4 * (l & 15);
    const int k0  = kc * 32 + (l >> 4) * 8;
    bf16x8 frag;
#pragma unroll
    for (int j = 0; j < 8; ++j)
        frag[j] = (short)f2bf(W2[(k0 + j) * 128 + col]);
    *(bf16x8*)&wf[(size_t)t * 8] = frag;
}

struct Pre {
    f4    xv[8];    // wave's 16x128 x-tile fragment slice (32 VGPR)
    float mfac[8];  // mask * decay factor for readback rows (8 VGPR)
};

__device__ __forceinline__ void prefetch_issue(const float* __restrict__ x,
                                               const int* __restrict__ mask,
                                               int tile, int wv, int l, int ln, int g,
                                               Pre& p) {
    const int row0 = tile * 64 + wv * 16;
    const float* xp = x + (long)(row0 + ln) * D_DIM + g * 8;
#pragma unroll
    for (int kc = 0; kc < 4; ++kc) {
        p.xv[2*kc]   = *(const f4*)(xp + kc*32);
        p.xv[2*kc+1] = *(const f4*)(xp + kc*32 + 4);
    }
#pragma unroll
    for (int i = 0; i < 8; ++i) {
        const int fr = row0 + 2*i + (l >> 5);
        const unsigned s = (unsigned)(fr & (S_LEN - 1));
        const float sc = (((s + 1u) % 10u) == 0u) ? 0.1f : 1.0f;
        p.mfac[i] = mask[fr] ? sc : 0.0f;
    }
}

__device__ __forceinline__ void compute_tile(int tile, const Pre& p,
    const u16* __restrict__ w1t, const u16* __restrict__ w2f, u16* __restrict__ hw,
    const float* b1f, const float* b2f,
    float* __restrict__ out, int wv, int l, int ln, int g) {

    const int row0 = tile * 64 + wv * 16;
    const f32x4 zero = {0.f, 0.f, 0.f, 0.f};

    // ---- convert prefetched x to bf16 A-fragments ----
    bf16x8 a[4];
#pragma unroll
    for (int kc = 0; kc < 4; ++kc) {
        const f4 lo = p.xv[2*kc], hi = p.xv[2*kc+1];
        bf16x8 t;
        t[0]=(short)f2bf(lo[0]); t[1]=(short)f2bf(lo[1]); t[2]=(short)f2bf(lo[2]); t[3]=(short)f2bf(lo[3]);
        t[4]=(short)f2bf(hi[0]); t[5]=(short)f2bf(hi[1]); t[6]=(short)f2bf(hi[2]); t[7]=(short)f2bf(hi[3]);
        a[kc] = t;
    }

    // ---- layer 1: H = X @ W1 from LDS (columns permuted: col = 64*(ct>>2)+(ct&3)+4*ln) ----
    f32x4 acc1[8];
#pragma unroll
    for (int ct = 0; ct < 8; ++ct) acc1[ct] = zero;
#pragma unroll
    for (int kc = 0; kc < 4; ++kc) {
        const int swu = (((kc*4 + g) ^ (ln & 7)) << 3);
#pragma unroll
        for (int ct = 0; ct < 8; ++ct) {
            const int col = (ct >> 2)*64 + (ct & 3) + 4*ln;
            const bf16x8 b = *(const bf16x8*)&w1t[col*128 + swu];
            acc1[ct] = __builtin_amdgcn_mfma_f32_16x16x32_bf16(a[kc], b, acc1[ct], 0, 0, 0);
        }
    }

    // ---- bias + silu -> h to per-wave LDS (swizzled, true-column layout) ----
#pragma unroll
    for (int hh = 0; hh < 2; ++hh) {
#pragma unroll
        for (int r = 0; r < 4; ++r) {
            const int row = g*4 + r;
            float z0 = acc1[hh*4+0][r] + b1f[hh*4+0];
            float z1 = acc1[hh*4+1][r] + b1f[hh*4+1];
            float z2 = acc1[hh*4+2][r] + b1f[hh*4+2];
            float z3 = acc1[hh*4+3][r] + b1f[hh*4+3];
            ushort4 pk;
            pk.x = f2bf(z0 / (1.f + __expf(-z0)));
            pk.y = f2bf(z1 / (1.f + __expf(-z1)));
            pk.z = f2bf(z2 / (1.f + __expf(-z2)));
            pk.w = f2bf(z3 / (1.f + __expf(-z3)));
            const int c0  = hh*64 + 4*ln;
            const int idx = row*128 + (((c0 >> 3) ^ (row & 7)) << 3) + (c0 & 7);
            *(ushort4*)&hw[idx] = pk;
        }
    }

    // ---- read h A-fragments (same-wave LDS round trip, no barrier) ----
    bf16x8 ha[4];
#pragma unroll
    for (int kc = 0; kc < 4; ++kc) {
        const int u = kc*4 + g;
        ha[kc] = *(const bf16x8*)&hw[ln*128 + ((u ^ (ln & 7)) << 3)];
    }

    // ---- layer 2: Y = H @ W2 — B-frags from global frag array (32 KB, L1-resident) ----
    f32x4 acc2[8];
#pragma unroll
    for (int ct = 0; ct < 8; ++ct) acc2[ct] = zero;
#pragma unroll
    for (int kc = 0; kc < 4; ++kc) {
#pragma unroll
        for (int ct = 0; ct < 8; ++ct) {
            const bf16x8 b = *(const bf16x8*)&w2f[(size_t)((kc*8 + ct)*64 + l) * 8];
            acc2[ct] = __builtin_amdgcn_mfma_f32_16x16x32_bf16(ha[kc], b, acc2[ct], 0, 0, 0);
        }
    }

    // ---- Y (+bias) -> bf16 back into the SAME per-wave buffer ----
#pragma unroll
    for (int hh = 0; hh < 2; ++hh) {
#pragma unroll
        for (int r = 0; r < 4; ++r) {
            const int row = g*4 + r;
            ushort4 pk;
            pk.x = f2bf(acc2[hh*4+0][r] + b2f[hh*4+0]);
            pk.y = f2bf(acc2[hh*4+1][r] + b2f[hh*4+1]);
            pk.z = f2bf(acc2[hh*4+2][r] + b2f[hh*4+2]);
            pk.w = f2bf(acc2[hh*4+3][r] + b2f[hh*4+3]);
            const int c0  = hh*64 + 4*ln;
            const int idx = row*128 + (((c0 >> 3) ^ (row & 7)) << 3) + (c0 & 7);
            *(ushort4*)&hw[idx] = pk;
        }
    }

    // ---- linear readback + mask/decay + lane-contiguous 1 KiB NONTEMPORAL stores ----
#pragma unroll
    for (int i = 0; i < 8; ++i) {
        const int row = 2*i + (l >> 5);
        const int c0  = 4 * (l & 31);
        const int u   = c0 >> 3;
        const int idx = row*128 + ((u ^ (row & 7)) << 3) + (c0 & 7);
        const ushort4 pk = *(const ushort4*)&hw[idx];
        f4 f;
        f[0] = bf2f(pk.x) * p.mfac[i];
        f[1] = bf2f(pk.y) * p.mfac[i];
        f[2] = bf2f(pk.z) * p.mfac[i];
        f[3] = bf2f(pk.w) * p.mfac[i];
        __builtin_nontemporal_store(f, (f4*)(out + (long)(row0 + row) * D_DIM + c0));
    }
}

__global__ void __launch_bounds__(256, 2)
ssm_fused_v14(const float* __restrict__ x,
              const int*   __restrict__ mask,
              const u16*   __restrict__ w2f,
              const float* __restrict__ W1,
              const float* __restrict__ b1,
              const float* __restrict__ b2,
              float* __restrict__ out) {
    // LDS: W1 (32 KiB) + h (16 KiB) = 48 KiB -> 3 blocks/CU, 12 waves/CU (3/SIMD)
    __shared__ __align__(16) u16 w1t[128*128];
    __shared__ __align__(16) u16 hlds[4*16*128];

    const int tid = threadIdx.x;
    const int l   = tid & 63;
    const int ln  = tid & 15;
    const int g   = (tid >> 4) & 3;
    const int wv  = tid >> 6;

    // ---- stage W1 as bf16, unit-swizzled:
    // elem (k, col) at col*128 + (((k>>3) ^ ((col>>2)&7))<<3) + (k&7)
    for (int i = tid; i < 4096; i += 256) {
        int k  = i >> 5;
        int n0 = (i & 31) * 4;
        float4 v1 = *(const float4*)(W1 + k*128 + n0);
        const float* p1 = (const float*)&v1;
#pragma unroll
        for (int j = 0; j < 4; ++j) {
            int n = n0 + j;
            int idx = n*128 + (((k >> 3) ^ ((n >> 2) & 7)) << 3) + (k & 7);
            w1t[idx] = f2bf(p1[j]);
        }
    }
    __syncthreads();

    // per-lane bias fragments at permuted columns
    float b1f[8], b2f[8];
#pragma unroll
    for (int ct = 0; ct < 8; ++ct) {
        const int col = (ct >> 2)*64 + (ct & 3) + 4*ln;
        b1f[ct] = b1[col];
        b2f[ct] = b2[col];
    }

    u16* hw = hlds + wv * 2048;

    // ---- software-pipelined main loop (ping-pong Pre, pinned issue points) ----
    Pre pa, pb;
    prefetch_issue(x, mask, blockIdx.x, wv, l, ln, g, pa);
    __builtin_amdgcn_sched_barrier(0);

#pragma unroll 1
    for (int itp = 0; itp < ITERS/2; ++itp) {
        const int tA = blockIdx.x + (2*itp) * NBLK;
        const int tB = tA + NBLK;
        int tC = tB + NBLK; if (tC >= NTILES) tC = tB;

        prefetch_issue(x, mask, tB, wv, l, ln, g, pb);
        __builtin_amdgcn_sched_barrier(0);
        compute_tile(tA, pa, w1t, w2f, hw, b1f, b2f, out, wv, l, ln, g);

        prefetch_issue(x, mask, tC, wv, l, ln, g, pa);
        __builtin_amdgcn_sched_barrier(0);
        compute_tile(tB, pb, w1t, w2f, hw, b1f, b2f, out, wv, l, ln, g);
    }
}

extern "C" void kernel_launch(void* const* d_in, const int* in_sizes, int n_in,
                              void* d_out, int out_size, void* d_ws, size_t ws_size,
                              hipStream_t stream) {
    const float* x    = (const float*)d_in[0];
    const int*   mask = (const int*)d_in[1];
    const float* W1   = (const float*)d_in[2];
    const float* b1   = (const float*)d_in[3];
    const float* W2   = (const float*)d_in[4];
    const float* b2   = (const float*)d_in[5];
    float* out = (float*)d_out;
    u16*   wf  = (u16*)d_ws;   // 32 KiB used (W2 frags)

    hipLaunchKernelGGL(prep_w2, dim3(8), dim3(256), 0, stream, W2, wf);
    hipLaunchKernelGGL(ssm_fused_v14, dim3(NBLK), dim3(256), 0, stream,
                       x, mask, wf, W1, b1, b2, out);
}

// Round 15
// 121.081 us; speedup vs baseline: 3.3292x; 1.0964x over previous
//
#include <hip/hip_runtime.h>
#include <hip/hip_bf16.h>

typedef short bf16x8 __attribute__((ext_vector_type(8)));
typedef float f32x4 __attribute__((ext_vector_type(4)));
typedef float f4    __attribute__((ext_vector_type(4)));
typedef unsigned short u16;

#define D_DIM  128
#define S_LEN  16384
#define NBLK   768       // 3 blocks/CU at 48 KiB LDS
#define NTILES 4096      // 262144 rows / 64 rows per block-tile (4 waves x 16 rows)

__device__ __forceinline__ u16 f2bf(float f) {
    __hip_bfloat16 h = __float2bfloat16(f);
    return __builtin_bit_cast(u16, h);
}

__device__ __forceinline__ float bf2f(u16 b) {
    unsigned u = ((unsigned)b) << 16;
    return __builtin_bit_cast(float, u);
}

// ---- prep: W2 (f32) -> bf16 MFMA B-fragment layout in d_ws ----
// frag f=kc*8+ct, lane l=(g=l>>4, ln=l&15), j=0..7:
//   element W2[kc*32 + g*8 + j][(ct>>2)*64 + (ct&3) + 4*ln]
// u16 index: f*512 + l*8 + j      [layout verified R12/R13/R14: absmax ok]
__global__ void __launch_bounds__(256)
prep_w2(const float* __restrict__ W2, u16* __restrict__ wf) {
    const int t  = blockIdx.x * 256 + threadIdx.x;   // 0..2047
    const int kc = (t >> 9) & 3;
    const int ct = (t >> 6) & 7;
    const int l  = t & 63;
    const int col = (ct >> 2) * 64 + (ct & 3) + 4 * (l & 15);
    const int k0  = kc * 32 + (l >> 4) * 8;
    bf16x8 frag;
#pragma unroll
    for (int j = 0; j < 8; ++j)
        frag[j] = (short)f2bf(W2[(k0 + j) * 128 + col]);
    *(bf16x8*)&wf[(size_t)t * 8] = frag;
}

struct Pre {
    f4    xv[8];    // wave's 16x128 x-tile fragment slice (32 VGPR)
    float mfac[8];  // mask * decay factor for readback rows (8 VGPR)
};

__device__ __forceinline__ void prefetch_issue(const float* __restrict__ x,
                                               const int* __restrict__ mask,
                                               int tile, int wv, int l, int ln, int g,
                                               Pre& p) {
    const int row0 = tile * 64 + wv * 16;
    const float* xp = x + (long)(row0 + ln) * D_DIM + g * 8;
#pragma unroll
    for (int kc = 0; kc < 4; ++kc) {
        p.xv[2*kc]   = *(const f4*)(xp + kc*32);
        p.xv[2*kc+1] = *(const f4*)(xp + kc*32 + 4);
    }
#pragma unroll
    for (int i = 0; i < 8; ++i) {
        const int fr = row0 + 2*i + (l >> 5);
        const unsigned s = (unsigned)(fr & (S_LEN - 1));
        const float sc = (((s + 1u) % 10u) == 0u) ? 0.1f : 1.0f;
        p.mfac[i] = mask[fr] ? sc : 0.0f;
    }
}

__device__ __forceinline__ void compute_tile(int tile, const Pre& p,
    const u16* __restrict__ w1t, const u16* __restrict__ w2f, u16* __restrict__ hw,
    const float* b1f, const float* b2f,
    float* __restrict__ out, int wv, int l, int ln, int g) {

    const int row0 = tile * 64 + wv * 16;
    const f32x4 zero = {0.f, 0.f, 0.f, 0.f};

    // ---- convert prefetched x to bf16 A-fragments ----
    bf16x8 a[4];
#pragma unroll
    for (int kc = 0; kc < 4; ++kc) {
        const f4 lo = p.xv[2*kc], hi = p.xv[2*kc+1];
        bf16x8 t;
        t[0]=(short)f2bf(lo[0]); t[1]=(short)f2bf(lo[1]); t[2]=(short)f2bf(lo[2]); t[3]=(short)f2bf(lo[3]);
        t[4]=(short)f2bf(hi[0]); t[5]=(short)f2bf(hi[1]); t[6]=(short)f2bf(hi[2]); t[7]=(short)f2bf(hi[3]);
        a[kc] = t;
    }

    // ---- layer 1: H = X @ W1 from LDS (columns permuted: col = 64*(ct>>2)+(ct&3)+4*ln) ----
    f32x4 acc1[8];
#pragma unroll
    for (int ct = 0; ct < 8; ++ct) acc1[ct] = zero;
#pragma unroll
    for (int kc = 0; kc < 4; ++kc) {
        const int swu = (((kc*4 + g) ^ (ln & 7)) << 3);
#pragma unroll
        for (int ct = 0; ct < 8; ++ct) {
            const int col = (ct >> 2)*64 + (ct & 3) + 4*ln;
            const bf16x8 b = *(const bf16x8*)&w1t[col*128 + swu];
            acc1[ct] = __builtin_amdgcn_mfma_f32_16x16x32_bf16(a[kc], b, acc1[ct], 0, 0, 0);
        }
    }

    // ---- bias + silu -> h to per-wave LDS (swizzled, true-column layout) ----
#pragma unroll
    for (int hh = 0; hh < 2; ++hh) {
#pragma unroll
        for (int r = 0; r < 4; ++r) {
            const int row = g*4 + r;
            float z0 = acc1[hh*4+0][r] + b1f[hh*4+0];
            float z1 = acc1[hh*4+1][r] + b1f[hh*4+1];
            float z2 = acc1[hh*4+2][r] + b1f[hh*4+2];
            float z3 = acc1[hh*4+3][r] + b1f[hh*4+3];
            ushort4 pk;
            pk.x = f2bf(z0 / (1.f + __expf(-z0)));
            pk.y = f2bf(z1 / (1.f + __expf(-z1)));
            pk.z = f2bf(z2 / (1.f + __expf(-z2)));
            pk.w = f2bf(z3 / (1.f + __expf(-z3)));
            const int c0  = hh*64 + 4*ln;
            const int idx = row*128 + (((c0 >> 3) ^ (row & 7)) << 3) + (c0 & 7);
            *(ushort4*)&hw[idx] = pk;
        }
    }

    // ---- read h A-fragments (same-wave LDS round trip, no barrier) ----
    bf16x8 ha[4];
#pragma unroll
    for (int kc = 0; kc < 4; ++kc) {
        const int u = kc*4 + g;
        ha[kc] = *(const bf16x8*)&hw[ln*128 + ((u ^ (ln & 7)) << 3)];
    }

    // ---- layer 2: Y = H @ W2 — B-frags from global frag array (32 KB, L2-resident),
    //      4-frag clusters, software-pipelined 1 ahead, sched_barrier-pinned so the
    //      scheduler can NEVER hoist more than 8 frags (32 VGPR) into flight. ----
    const u16* wp = w2f + (size_t)l * 8;
    f32x4 acc2[8];
#pragma unroll
    for (int ct = 0; ct < 8; ++ct) acc2[ct] = zero;

    bf16x8 wA0, wA1, wA2, wA3, wB0, wB1, wB2, wB3;
    wA0 = *(const bf16x8*)&wp[0*512]; wA1 = *(const bf16x8*)&wp[1*512];
    wA2 = *(const bf16x8*)&wp[2*512]; wA3 = *(const bf16x8*)&wp[3*512];
    __builtin_amdgcn_sched_barrier(0);
#pragma unroll
    for (int kc = 0; kc < 4; ++kc) {
        const int fB = kc*8 + 4;
        wB0 = *(const bf16x8*)&wp[(fB+0)*512]; wB1 = *(const bf16x8*)&wp[(fB+1)*512];
        wB2 = *(const bf16x8*)&wp[(fB+2)*512]; wB3 = *(const bf16x8*)&wp[(fB+3)*512];
        __builtin_amdgcn_sched_barrier(0);
        acc2[0] = __builtin_amdgcn_mfma_f32_16x16x32_bf16(ha[kc], wA0, acc2[0], 0, 0, 0);
        acc2[1] = __builtin_amdgcn_mfma_f32_16x16x32_bf16(ha[kc], wA1, acc2[1], 0, 0, 0);
        acc2[2] = __builtin_amdgcn_mfma_f32_16x16x32_bf16(ha[kc], wA2, acc2[2], 0, 0, 0);
        acc2[3] = __builtin_amdgcn_mfma_f32_16x16x32_bf16(ha[kc], wA3, acc2[3], 0, 0, 0);
        const int fA = ((kc+1)*8) & 31;       // kc=3: dummy re-read of frags 0-3 (harmless)
        wA0 = *(const bf16x8*)&wp[(fA+0)*512]; wA1 = *(const bf16x8*)&wp[(fA+1)*512];
        wA2 = *(const bf16x8*)&wp[(fA+2)*512]; wA3 = *(const bf16x8*)&wp[(fA+3)*512];
        __builtin_amdgcn_sched_barrier(0);
        acc2[4] = __builtin_amdgcn_mfma_f32_16x16x32_bf16(ha[kc], wB0, acc2[4], 0, 0, 0);
        acc2[5] = __builtin_amdgcn_mfma_f32_16x16x32_bf16(ha[kc], wB1, acc2[5], 0, 0, 0);
        acc2[6] = __builtin_amdgcn_mfma_f32_16x16x32_bf16(ha[kc], wB2, acc2[6], 0, 0, 0);
        acc2[7] = __builtin_amdgcn_mfma_f32_16x16x32_bf16(ha[kc], wB3, acc2[7], 0, 0, 0);
    }

    // ---- Y (+bias) -> bf16 back into the SAME per-wave buffer ----
#pragma unroll
    for (int hh = 0; hh < 2; ++hh) {
#pragma unroll
        for (int r = 0; r < 4; ++r) {
            const int row = g*4 + r;
            ushort4 pk;
            pk.x = f2bf(acc2[hh*4+0][r] + b2f[hh*4+0]);
            pk.y = f2bf(acc2[hh*4+1][r] + b2f[hh*4+1]);
            pk.z = f2bf(acc2[hh*4+2][r] + b2f[hh*4+2]);
            pk.w = f2bf(acc2[hh*4+3][r] + b2f[hh*4+3]);
            const int c0  = hh*64 + 4*ln;
            const int idx = row*128 + (((c0 >> 3) ^ (row & 7)) << 3) + (c0 & 7);
            *(ushort4*)&hw[idx] = pk;
        }
    }

    // ---- linear readback + mask/decay + lane-contiguous 1 KiB NONTEMPORAL stores ----
#pragma unroll
    for (int i = 0; i < 8; ++i) {
        const int row = 2*i + (l >> 5);
        const int c0  = 4 * (l & 31);
        const int u   = c0 >> 3;
        const int idx = row*128 + ((u ^ (row & 7)) << 3) + (c0 & 7);
        const ushort4 pk = *(const ushort4*)&hw[idx];
        f4 f;
        f[0] = bf2f(pk.x) * p.mfac[i];
        f[1] = bf2f(pk.y) * p.mfac[i];
        f[2] = bf2f(pk.z) * p.mfac[i];
        f[3] = bf2f(pk.w) * p.mfac[i];
        __builtin_nontemporal_store(f, (f4*)(out + (long)(row0 + row) * D_DIM + c0));
    }
}

__global__ void __launch_bounds__(256, 2)
ssm_fused_v15(const float* __restrict__ x,
              const int*   __restrict__ mask,
              const u16*   __restrict__ w2f,
              const float* __restrict__ W1,
              const float* __restrict__ b1,
              const float* __restrict__ b2,
              float* __restrict__ out) {
    // LDS: W1 (32 KiB) + h (16 KiB) = 48 KiB -> 3 blocks/CU, 12 waves/CU (3/SIMD)
    __shared__ __align__(16) u16 w1t[128*128];
    __shared__ __align__(16) u16 hlds[4*16*128];

    const int tid = threadIdx.x;
    const int l   = tid & 63;
    const int ln  = tid & 15;
    const int g   = (tid >> 4) & 3;
    const int wv  = tid >> 6;

    // ---- stage W1 as bf16, unit-swizzled:
    // elem (k, col) at col*128 + (((k>>3) ^ ((col>>2)&7))<<3) + (k&7)
    for (int i = tid; i < 4096; i += 256) {
        int k  = i >> 5;
        int n0 = (i & 31) * 4;
        float4 v1 = *(const float4*)(W1 + k*128 + n0);
        const float* p1 = (const float*)&v1;
#pragma unroll
        for (int j = 0; j < 4; ++j) {
            int n = n0 + j;
            int idx = n*128 + (((k >> 3) ^ ((n >> 2) & 7)) << 3) + (k & 7);
            w1t[idx] = f2bf(p1[j]);
        }
    }
    __syncthreads();

    // per-lane bias fragments at permuted columns
    float b1f[8], b2f[8];
#pragma unroll
    for (int ct = 0; ct < 8; ++ct) {
        const int col = (ct >> 2)*64 + (ct & 3) + 4*ln;
        b1f[ct] = b1[col];
        b2f[ct] = b2[col];
    }

    u16* hw = hlds + wv * 2048;

    // ---- software-pipelined main loop (ping-pong Pre, pinned issue points).
    //      Blocks 0..255 run 6 tiles, 256..767 run 5 (block-uniform guard). ----
    Pre pa, pb;
    prefetch_issue(x, mask, blockIdx.x, wv, l, ln, g, pa);
    __builtin_amdgcn_sched_barrier(0);

#pragma unroll 1
    for (int itp = 0; itp < 3; ++itp) {
        const int tA = blockIdx.x + (2*itp) * NBLK;
        const int tB = tA + NBLK;
        const bool hasB = tB < NTILES;
        int tC = tB + NBLK; if (tC >= NTILES) tC = hasB ? tB : tA;

        prefetch_issue(x, mask, hasB ? tB : tA, wv, l, ln, g, pb);
        __builtin_amdgcn_sched_barrier(0);
        compute_tile(tA, pa, w1t, w2f, hw, b1f, b2f, out, wv, l, ln, g);
        if (!hasB) break;

        prefetch_issue(x, mask, tC, wv, l, ln, g, pa);
        __builtin_amdgcn_sched_barrier(0);
        compute_tile(tB, pb, w1t, w2f, hw, b1f, b2f, out, wv, l, ln, g);
    }
}

extern "C" void kernel_launch(void* const* d_in, const int* in_sizes, int n_in,
                              void* d_out, int out_size, void* d_ws, size_t ws_size,
                              hipStream_t stream) {
    const float* x    = (const float*)d_in[0];
    const int*   mask = (const int*)d_in[1];
    const float* W1   = (const float*)d_in[2];
    const float* b1   = (const float*)d_in[3];
    const float* W2   = (const float*)d_in[4];
    const float* b2   = (const float*)d_in[5];
    float* out = (float*)d_out;
    u16*   wf  = (u16*)d_ws;   // 32 KiB used (W2 frags)

    hipLaunchKernelGGL(prep_w2, dim3(8), dim3(256), 0, stream, W2, wf);
    hipLaunchKernelGGL(ssm_fused_v15, dim3(NBLK), dim3(256), 0, stream,
                       x, mask, wf, W1, b1, b2, out);
}

// Round 16
// 63.729 us; speedup vs baseline: 6.3253x; 1.8999x over previous
//
#include <hip/hip_runtime.h>
#include <hip/hip_bf16.h>

typedef short bf16x8 __attribute__((ext_vector_type(8)));
typedef float f32x4 __attribute__((ext_vector_type(4)));
typedef float f4    __attribute__((ext_vector_type(4)));
typedef unsigned short u16;

#define D_DIM  128
#define S_LEN  16384
#define NBLK   512
#define NTILES 4096      // 262144 rows / 64 rows per block-tile (4 waves x 16 rows)
#define ITERS  8         // NTILES / NBLK

__device__ __forceinline__ u16 f2bf(float f) {
    __hip_bfloat16 h = __float2bfloat16(f);
    return __builtin_bit_cast(u16, h);
}

__device__ __forceinline__ float bf2f(u16 b) {
    unsigned u = ((unsigned)b) << 16;
    return __builtin_bit_cast(float, u);
}

// ---- prep: W1,W2 (f32) -> bf16 MFMA B-fragment layout in d_ws ----
// frag(L,kc,ct), lane l=(g=l>>4, ln=l&15), j=0..7:
//   element W_L[kc*32 + g*8 + j][(ct>>2)*64 + (ct&3) + 4*ln]
// flat u16 index: (((L*4+kc)*8+ct)*64 + l)*8 + j   [verified R12-R15: absmax ok]
__global__ void __launch_bounds__(256)
prep_weights(const float* __restrict__ W1, const float* __restrict__ W2,
             u16* __restrict__ wf) {
    const int t  = blockIdx.x * 256 + threadIdx.x;   // 0..4095
    const int L  = t >> 11;
    const int kc = (t >> 9) & 3;
    const int ct = (t >> 6) & 7;
    const int l  = t & 63;
    const float* W = L ? W2 : W1;
    const int col = (ct >> 2) * 64 + (ct & 3) + 4 * (l & 15);
    const int k0  = kc * 32 + (l >> 4) * 8;
    bf16x8 frag;
#pragma unroll
    for (int j = 0; j < 8; ++j)
        frag[j] = (short)f2bf(W[(k0 + j) * 128 + col]);
    *(bf16x8*)&wf[(size_t)t * 8] = frag;
}

struct Pre {
    f4    xv[8];    // wave's 16x128 x-tile fragment slice (32 VGPR)
    float mfac[8];  // mask * decay factor for readback rows (8 VGPR)
};

__device__ __forceinline__ void prefetch_issue(const float* __restrict__ x,
                                               const int* __restrict__ mask,
                                               int tile, int wv, int l, int ln, int g,
                                               Pre& p) {
    const int row0 = tile * 64 + wv * 16;
    const float* xp = x + (long)(row0 + ln) * D_DIM + g * 8;
#pragma unroll
    for (int kc = 0; kc < 4; ++kc) {
        p.xv[2*kc]   = *(const f4*)(xp + kc*32);
        p.xv[2*kc+1] = *(const f4*)(xp + kc*32 + 4);
    }
#pragma unroll
    for (int i = 0; i < 8; ++i) {
        const int fr = row0 + 2*i + (l >> 5);
        const unsigned s = (unsigned)(fr & (S_LEN - 1));
        const float sc = (((s + 1u) % 10u) == 0u) ? 0.1f : 1.0f;
        p.mfac[i] = mask[fr] ? sc : 0.0f;
    }
}

__device__ __forceinline__ void compute_tile(int tile, const Pre& p,
    const u16* __restrict__ w1f, const u16* __restrict__ w2f, u16* __restrict__ hw,
    const float* b1f, const float* b2f,
    float* __restrict__ out, int wv, int l, int ln, int g) {

    const int row0 = tile * 64 + wv * 16;
    const f32x4 zero = {0.f, 0.f, 0.f, 0.f};

    // ---- convert prefetched x to bf16 A-fragments ----
    bf16x8 a[4];
#pragma unroll
    for (int kc = 0; kc < 4; ++kc) {
        const f4 lo = p.xv[2*kc], hi = p.xv[2*kc+1];
        bf16x8 t;
        t[0]=(short)f2bf(lo[0]); t[1]=(short)f2bf(lo[1]); t[2]=(short)f2bf(lo[2]); t[3]=(short)f2bf(lo[3]);
        t[4]=(short)f2bf(hi[0]); t[5]=(short)f2bf(hi[1]); t[6]=(short)f2bf(hi[2]); t[7]=(short)f2bf(hi[3]);
        a[kc] = t;
    }

    // ---- layer 1: H = X @ W1 — frag-layout LDS reads: one addr reg (l*16B),
    //      compile-time offset per frag, lane-linear 1KB per read = conflict-free ----
    f32x4 acc1[8];
#pragma unroll
    for (int ct = 0; ct < 8; ++ct) acc1[ct] = zero;
#pragma unroll
    for (int kc = 0; kc < 4; ++kc) {
#pragma unroll
        for (int ct = 0; ct < 8; ++ct) {
            const bf16x8 b = *(const bf16x8*)&w1f[(kc*8 + ct)*512 + l*8];
            acc1[ct] = __builtin_amdgcn_mfma_f32_16x16x32_bf16(a[kc], b, acc1[ct], 0, 0, 0);
        }
    }

    // ---- bias + silu -> h to per-wave LDS (swizzled, true-column layout) ----
#pragma unroll
    for (int hh = 0; hh < 2; ++hh) {
#pragma unroll
        for (int r = 0; r < 4; ++r) {
            const int row = g*4 + r;
            float z0 = acc1[hh*4+0][r] + b1f[hh*4+0];
            float z1 = acc1[hh*4+1][r] + b1f[hh*4+1];
            float z2 = acc1[hh*4+2][r] + b1f[hh*4+2];
            float z3 = acc1[hh*4+3][r] + b1f[hh*4+3];
            ushort4 pk;
            pk.x = f2bf(z0 / (1.f + __expf(-z0)));
            pk.y = f2bf(z1 / (1.f + __expf(-z1)));
            pk.z = f2bf(z2 / (1.f + __expf(-z2)));
            pk.w = f2bf(z3 / (1.f + __expf(-z3)));
            const int c0  = hh*64 + 4*ln;
            const int idx = row*128 + (((c0 >> 3) ^ (row & 7)) << 3) + (c0 & 7);
            *(ushort4*)&hw[idx] = pk;
        }
    }

    // ---- read h A-fragments (same-wave LDS round trip, no barrier) ----
    bf16x8 ha[4];
#pragma unroll
    for (int kc = 0; kc < 4; ++kc) {
        const int u = kc*4 + g;
        ha[kc] = *(const bf16x8*)&hw[ln*128 + ((u ^ (ln & 7)) << 3)];
    }

    // ---- layer 2: Y = H @ W2 — same frag-layout LDS reads ----
    f32x4 acc2[8];
#pragma unroll
    for (int ct = 0; ct < 8; ++ct) acc2[ct] = zero;
#pragma unroll
    for (int kc = 0; kc < 4; ++kc) {
#pragma unroll
        for (int ct = 0; ct < 8; ++ct) {
            const bf16x8 b = *(const bf16x8*)&w2f[(kc*8 + ct)*512 + l*8];
            acc2[ct] = __builtin_amdgcn_mfma_f32_16x16x32_bf16(ha[kc], b, acc2[ct], 0, 0, 0);
        }
    }

    // ---- Y (+bias) -> bf16 back into the SAME per-wave buffer ----
#pragma unroll
    for (int hh = 0; hh < 2; ++hh) {
#pragma unroll
        for (int r = 0; r < 4; ++r) {
            const int row = g*4 + r;
            ushort4 pk;
            pk.x = f2bf(acc2[hh*4+0][r] + b2f[hh*4+0]);
            pk.y = f2bf(acc2[hh*4+1][r] + b2f[hh*4+1]);
            pk.z = f2bf(acc2[hh*4+2][r] + b2f[hh*4+2]);
            pk.w = f2bf(acc2[hh*4+3][r] + b2f[hh*4+3]);
            const int c0  = hh*64 + 4*ln;
            const int idx = row*128 + (((c0 >> 3) ^ (row & 7)) << 3) + (c0 & 7);
            *(ushort4*)&hw[idx] = pk;
        }
    }

    // ---- linear readback + mask/decay + lane-contiguous 1 KiB NONTEMPORAL stores ----
#pragma unroll
    for (int i = 0; i < 8; ++i) {
        const int row = 2*i + (l >> 5);
        const int c0  = 4 * (l & 31);
        const int u   = c0 >> 3;
        const int idx = row*128 + ((u ^ (row & 7)) << 3) + (c0 & 7);
        const ushort4 pk = *(const ushort4*)&hw[idx];
        f4 f;
        f[0] = bf2f(pk.x) * p.mfac[i];
        f[1] = bf2f(pk.y) * p.mfac[i];
        f[2] = bf2f(pk.z) * p.mfac[i];
        f[3] = bf2f(pk.w) * p.mfac[i];
        __builtin_nontemporal_store(f, (f4*)(out + (long)(row0 + row) * D_DIM + c0));
    }
}

__global__ void __launch_bounds__(256, 2)
ssm_fused_v16(const float* __restrict__ x,
              const int*   __restrict__ mask,
              const u16*   __restrict__ wf,
              const float* __restrict__ b1,
              const float* __restrict__ b2,
              float* __restrict__ out) {
    // LDS: weight frags (64 KiB) + h (16 KiB) = 80 KiB -> 2 blocks/CU
    __shared__ __align__(16) u16 wlds[2*16384];
    __shared__ __align__(16) u16 hlds[4*16*128];

    const int tid = threadIdx.x;
    const int l   = tid & 63;
    const int ln  = tid & 15;
    const int g   = (tid >> 4) & 3;
    const int wv  = tid >> 6;

    // ---- stage weight frags: linear 16B/lane copy from prepped global array ----
    {
        const f4* src = (const f4*)wf;      // 4096 x 16B = 64 KiB
        f4* dst = (f4*)wlds;
        for (int i = tid; i < 4096; i += 256)
            dst[i] = src[i];
    }
    __syncthreads();

    const u16* w1f = wlds;            // frag f at u16 offset f*512 + l*8
    const u16* w2f = wlds + 16384;

    // per-lane bias fragments at permuted columns
    float b1f[8], b2f[8];
#pragma unroll
    for (int ct = 0; ct < 8; ++ct) {
        const int col = (ct >> 2)*64 + (ct & 3) + 4*ln;
        b1f[ct] = b1[col];
        b2f[ct] = b2[col];
    }

    u16* hw = hlds + wv * 2048;

    // ---- software-pipelined main loop (ping-pong Pre, pinned issue points) ----
    Pre pa, pb;
    prefetch_issue(x, mask, blockIdx.x, wv, l, ln, g, pa);
    __builtin_amdgcn_sched_barrier(0);

#pragma unroll 1
    for (int itp = 0; itp < ITERS/2; ++itp) {
        const int tA = blockIdx.x + (2*itp) * NBLK;
        const int tB = tA + NBLK;
        int tC = tB + NBLK; if (tC >= NTILES) tC = tB;

        prefetch_issue(x, mask, tB, wv, l, ln, g, pb);
        __builtin_amdgcn_sched_barrier(0);
        compute_tile(tA, pa, w1f, w2f, hw, b1f, b2f, out, wv, l, ln, g);

        prefetch_issue(x, mask, tC, wv, l, ln, g, pa);
        __builtin_amdgcn_sched_barrier(0);
        compute_tile(tB, pb, w1f, w2f, hw, b1f, b2f, out, wv, l, ln, g);
    }
}

extern "C" void kernel_launch(void* const* d_in, const int* in_sizes, int n_in,
                              void* d_out, int out_size, void* d_ws, size_t ws_size,
                              hipStream_t stream) {
    const float* x    = (const float*)d_in[0];
    const int*   mask = (const int*)d_in[1];
    const float* W1   = (const float*)d_in[2];
    const float* b1   = (const float*)d_in[3];
    const float* W2   = (const float*)d_in[4];
    const float* b2   = (const float*)d_in[5];
    float* out = (float*)d_out;
    u16*   wf  = (u16*)d_ws;   // 64 KiB used (W1+W2 frags)

    hipLaunchKernelGGL(prep_weights, dim3(16), dim3(256), 0, stream, W1, W2, wf);
    hipLaunchKernelGGL(ssm_fused_v16, dim3(NBLK), dim3(256), 0, stream,
                       x, mask, wf, b1, b2, out);
}

// Round 17
// 59.904 us; speedup vs baseline: 6.7292x; 1.0638x over previous
//
#include <hip/hip_runtime.h>
#include <hip/hip_bf16.h>

typedef short bf16x8 __attribute__((ext_vector_type(8)));
typedef float f32x4 __attribute__((ext_vector_type(4)));
typedef float f4    __attribute__((ext_vector_type(4)));
typedef unsigned short u16;

#define D_DIM  128
#define S_LEN  16384
#define NBLK   512
#define NTILES 4096      // 262144 rows / 64 rows per block-tile (4 waves x 16 rows)
#define ITERS  8         // NTILES / NBLK

__device__ __forceinline__ u16 f2bf(float f) {
    __hip_bfloat16 h = __float2bfloat16(f);
    return __builtin_bit_cast(u16, h);
}

__device__ __forceinline__ float bf2f(u16 b) {
    unsigned u = ((unsigned)b) << 16;
    return __builtin_bit_cast(float, u);
}

struct Pre {
    f4    xv[8];    // wave's 16x128 x-tile fragment slice (32 VGPR)
    float mfac[8];  // mask * decay factor for readback rows (8 VGPR)
};

// Issue next tile's loads; call site must follow with sched_barrier(0)
// so VMEM cannot sink down to its (far) uses.
__device__ __forceinline__ void prefetch_issue(const float* __restrict__ x,
                                               const int* __restrict__ mask,
                                               int tile, int wv, int l, int ln, int g,
                                               Pre& p) {
    const int row0 = tile * 64 + wv * 16;
    const float* xp = x + (long)(row0 + ln) * D_DIM + g * 8;
#pragma unroll
    for (int kc = 0; kc < 4; ++kc) {
        p.xv[2*kc]   = *(const f4*)(xp + kc*32);
        p.xv[2*kc+1] = *(const f4*)(xp + kc*32 + 4);
    }
    // mask + hard-reset decay for readback rows: frame = row0 + 2i + (l>>5)
#pragma unroll
    for (int i = 0; i < 8; ++i) {
        const int fr = row0 + 2*i + (l >> 5);
        const unsigned s = (unsigned)(fr & (S_LEN - 1));
        const float sc = (((s + 1u) % 10u) == 0u) ? 0.1f : 1.0f;
        p.mfac[i] = mask[fr] ? sc : 0.0f;
    }
}

__device__ __forceinline__ void compute_tile(int tile, const Pre& p,
    const u16* __restrict__ w1f, const u16* __restrict__ w2f, u16* __restrict__ hw,
    const float* b1f, const float* b2f,
    float* __restrict__ out, int wv, int l, int ln, int g) {

    const int row0 = tile * 64 + wv * 16;
    const f32x4 zero = {0.f, 0.f, 0.f, 0.f};

    // ---- convert prefetched x to bf16 A-fragments ----
    bf16x8 a[4];
#pragma unroll
    for (int kc = 0; kc < 4; ++kc) {
        const f4 lo = p.xv[2*kc], hi = p.xv[2*kc+1];
        bf16x8 t;
        t[0]=(short)f2bf(lo[0]); t[1]=(short)f2bf(lo[1]); t[2]=(short)f2bf(lo[2]); t[3]=(short)f2bf(lo[3]);
        t[4]=(short)f2bf(hi[0]); t[5]=(short)f2bf(hi[1]); t[6]=(short)f2bf(hi[2]); t[7]=(short)f2bf(hi[3]);
        a[kc] = t;
    }

    // ---- layer 1: H = X @ W1 — frag-layout LDS reads: one addr reg (l*16B),
    //      compile-time offset per frag, lane-linear 1KB per read = conflict-free ----
    f32x4 acc1[8];
#pragma unroll
    for (int ct = 0; ct < 8; ++ct) acc1[ct] = zero;
#pragma unroll
    for (int kc = 0; kc < 4; ++kc) {
#pragma unroll
        for (int ct = 0; ct < 8; ++ct) {
            const bf16x8 b = *(const bf16x8*)&w1f[(kc*8 + ct)*512 + l*8];
            acc1[ct] = __builtin_amdgcn_mfma_f32_16x16x32_bf16(a[kc], b, acc1[ct], 0, 0, 0);
        }
    }

    // ---- bias + silu -> h to per-wave LDS (swizzled, true-column layout) ----
#pragma unroll
    for (int hh = 0; hh < 2; ++hh) {
#pragma unroll
        for (int r = 0; r < 4; ++r) {
            const int row = g*4 + r;
            float z0 = acc1[hh*4+0][r] + b1f[hh*4+0];
            float z1 = acc1[hh*4+1][r] + b1f[hh*4+1];
            float z2 = acc1[hh*4+2][r] + b1f[hh*4+2];
            float z3 = acc1[hh*4+3][r] + b1f[hh*4+3];
            ushort4 pk;
            pk.x = f2bf(z0 / (1.f + __expf(-z0)));
            pk.y = f2bf(z1 / (1.f + __expf(-z1)));
            pk.z = f2bf(z2 / (1.f + __expf(-z2)));
            pk.w = f2bf(z3 / (1.f + __expf(-z3)));
            const int c0  = hh*64 + 4*ln;
            const int idx = row*128 + (((c0 >> 3) ^ (row & 7)) << 3) + (c0 & 7);
            *(ushort4*)&hw[idx] = pk;
        }
    }

    // ---- read h A-fragments (same-wave LDS round trip, no barrier) ----
    bf16x8 ha[4];
#pragma unroll
    for (int kc = 0; kc < 4; ++kc) {
        const int u = kc*4 + g;
        ha[kc] = *(const bf16x8*)&hw[ln*128 + ((u ^ (ln & 7)) << 3)];
    }

    // ---- layer 2: Y = H @ W2 — same frag-layout LDS reads ----
    f32x4 acc2[8];
#pragma unroll
    for (int ct = 0; ct < 8; ++ct) acc2[ct] = zero;
#pragma unroll
    for (int kc = 0; kc < 4; ++kc) {
#pragma unroll
        for (int ct = 0; ct < 8; ++ct) {
            const bf16x8 b = *(const bf16x8*)&w2f[(kc*8 + ct)*512 + l*8];
            acc2[ct] = __builtin_amdgcn_mfma_f32_16x16x32_bf16(ha[kc], b, acc2[ct], 0, 0, 0);
        }
    }

    // ---- Y (+bias) -> bf16 back into the SAME per-wave buffer ----
#pragma unroll
    for (int hh = 0; hh < 2; ++hh) {
#pragma unroll
        for (int r = 0; r < 4; ++r) {
            const int row = g*4 + r;
            ushort4 pk;
            pk.x = f2bf(acc2[hh*4+0][r] + b2f[hh*4+0]);
            pk.y = f2bf(acc2[hh*4+1][r] + b2f[hh*4+1]);
            pk.z = f2bf(acc2[hh*4+2][r] + b2f[hh*4+2]);
            pk.w = f2bf(acc2[hh*4+3][r] + b2f[hh*4+3]);
            const int c0  = hh*64 + 4*ln;
            const int idx = row*128 + (((c0 >> 3) ^ (row & 7)) << 3) + (c0 & 7);
            *(ushort4*)&hw[idx] = pk;
        }
    }

    // ---- linear readback + mask/decay + lane-contiguous 1 KiB NONTEMPORAL stores ----
#pragma unroll
    for (int i = 0; i < 8; ++i) {
        const int row = 2*i + (l >> 5);
        const int c0  = 4 * (l & 31);
        const int u   = c0 >> 3;
        const int idx = row*128 + ((u ^ (row & 7)) << 3) + (c0 & 7);
        const ushort4 pk = *(const ushort4*)&hw[idx];
        f4 f;
        f[0] = bf2f(pk.x) * p.mfac[i];
        f[1] = bf2f(pk.y) * p.mfac[i];
        f[2] = bf2f(pk.z) * p.mfac[i];
        f[3] = bf2f(pk.w) * p.mfac[i];
        __builtin_nontemporal_store(f, (f4*)(out + (long)(row0 + row) * D_DIM + c0));
    }
}

__global__ void __launch_bounds__(256, 2)
ssm_fused_v17(const float* __restrict__ x,
              const int*   __restrict__ mask,
              const float* __restrict__ W1,
              const float* __restrict__ b1,
              const float* __restrict__ W2,
              const float* __restrict__ b2,
              float* __restrict__ out) {
    // LDS: weight frags (64 KiB) + h (16 KiB) = 80 KiB -> 2 blocks/CU
    __shared__ __align__(16) u16 wlds[2*16384];
    __shared__ __align__(16) u16 hlds[4*16*128];

    const int tid = threadIdx.x;
    const int l   = tid & 63;
    const int ln  = tid & 15;
    const int g   = (tid >> 4) & 3;
    const int wv  = tid >> 6;

    // ---- stage W1,W2 as bf16 directly in MFMA FRAG LAYOUT (fused prep):
    // element (k,col) of layer L -> wlds[L*16384 + (kc*8+ct)*512 + lane*8 + j]
    //   kc=k>>5, gg=(k>>3)&3, j=k&7, ct=(col>>6)*4+(col&3), lnn=(col&63)>>2, lane=gg*16+lnn
    for (int i = tid; i < 4096; i += 256) {
        int k  = i >> 5;
        int n0 = (i & 31) * 4;
        float4 v1 = *(const float4*)(W1 + k*128 + n0);
        float4 v2 = *(const float4*)(W2 + k*128 + n0);
        const float* p1 = (const float*)&v1;
        const float* p2 = (const float*)&v2;
        const int kc = k >> 5;
        const int gg = (k >> 3) & 3;
        const int j  = k & 7;
#pragma unroll
        for (int jj = 0; jj < 4; ++jj) {
            const int col = n0 + jj;
            const int ct  = ((col >> 6) << 2) + (col & 3);
            const int lnn = (col & 63) >> 2;
            const int idx = (kc*8 + ct)*512 + (gg*16 + lnn)*8 + j;
            wlds[idx]         = f2bf(p1[jj]);
            wlds[16384 + idx] = f2bf(p2[jj]);
        }
    }
    __syncthreads();

    const u16* w1f = wlds;            // frag f at u16 offset f*512 + l*8
    const u16* w2f = wlds + 16384;

    // per-lane bias fragments at permuted columns
    float b1f[8], b2f[8];
#pragma unroll
    for (int ct = 0; ct < 8; ++ct) {
        const int col = (ct >> 2)*64 + (ct & 3) + 4*ln;
        b1f[ct] = b1[col];
        b2f[ct] = b2[col];
    }

    u16* hw = hlds + wv * 2048;

    // ---- software-pipelined main loop (ping-pong Pre, pinned issue points) ----
    Pre pa, pb;
    prefetch_issue(x, mask, blockIdx.x, wv, l, ln, g, pa);
    __builtin_amdgcn_sched_barrier(0);

#pragma unroll 1
    for (int itp = 0; itp < ITERS/2; ++itp) {
        const int tA = blockIdx.x + (2*itp) * NBLK;
        const int tB = tA + NBLK;
        int tC = tB + NBLK; if (tC >= NTILES) tC = tB;

        prefetch_issue(x, mask, tB, wv, l, ln, g, pb);
        __builtin_amdgcn_sched_barrier(0);
        compute_tile(tA, pa, w1f, w2f, hw, b1f, b2f, out, wv, l, ln, g);

        prefetch_issue(x, mask, tC, wv, l, ln, g, pa);
        __builtin_amdgcn_sched_barrier(0);
        compute_tile(tB, pb, w1f, w2f, hw, b1f, b2f, out, wv, l, ln, g);
    }
}

extern "C" void kernel_launch(void* const* d_in, const int* in_sizes, int n_in,
                              void* d_out, int out_size, void* d_ws, size_t ws_size,
                              hipStream_t stream) {
    const float* x    = (const float*)d_in[0];
    const int*   mask = (const int*)d_in[1];
    const float* W1   = (const float*)d_in[2];
    const float* b1   = (const float*)d_in[3];
    const float* W2   = (const float*)d_in[4];
    const float* b2   = (const float*)d_in[5];
    float* out = (float*)d_out;

    hipLaunchKernelGGL(ssm_fused_v17, dim3(NBLK), dim3(256), 0, stream,
                       x, mask, W1, b1, W2, b2, out);
}

// Round 18
// 54.208 us; speedup vs baseline: 7.4362x; 1.1051x over previous
//
#include <hip/hip_runtime.h>
#include <hip/hip_bf16.h>

typedef short bf16x8 __attribute__((ext_vector_type(8)));
typedef float f32x4 __attribute__((ext_vector_type(4)));
typedef float f4    __attribute__((ext_vector_type(4)));
typedef unsigned short u16;

#define D_DIM  128
#define S_LEN  16384
#define NBLK   512
#define NTILES 4096      // 262144 rows / 64 rows per block-tile (4 waves x 16 rows)
#define ITERS  8         // NTILES / NBLK

__device__ __forceinline__ u16 f2bf(float f) {
    __hip_bfloat16 h = __float2bfloat16(f);
    return __builtin_bit_cast(u16, h);
}

struct Pre {
    f4    xv[8];    // wave's 16x128 x-tile fragment slice (32 VGPR)
    float mfac[4];  // mask * decay for this thread's MFMA rows (row0 + g*4 + i)
};

// Issue next tile's loads; call site must follow with sched_barrier(0)
// so VMEM cannot sink down to its (far) uses.
__device__ __forceinline__ void prefetch_issue(const float* __restrict__ x,
                                               const int* __restrict__ mask,
                                               int tile, int wv, int ln, int g,
                                               Pre& p) {
    const int row0 = tile * 64 + wv * 16;
    const float* xp = x + (long)(row0 + ln) * D_DIM + g * 8;
#pragma unroll
    for (int kc = 0; kc < 4; ++kc) {
        p.xv[2*kc]   = *(const f4*)(xp + kc*32);
        p.xv[2*kc+1] = *(const f4*)(xp + kc*32 + 4);
    }
    // mask + hard-reset decay for this thread's output rows: frame = row0 + g*4 + i
#pragma unroll
    for (int i = 0; i < 4; ++i) {
        const int fr = row0 + g*4 + i;
        const unsigned s = (unsigned)(fr & (S_LEN - 1));
        const float sc = (((s + 1u) % 10u) == 0u) ? 0.1f : 1.0f;
        p.mfac[i] = mask[fr] ? sc : 0.0f;
    }
}

__device__ __forceinline__ void compute_tile(int tile, const Pre& p,
    const u16* __restrict__ w1f, const u16* __restrict__ w2f, u16* __restrict__ hw,
    const float* b1f, const float* b2f,
    float* __restrict__ out, int wv, int l, int ln, int g) {

    const int row0 = tile * 64 + wv * 16;
    const f32x4 zero = {0.f, 0.f, 0.f, 0.f};

    // ---- convert prefetched x to bf16 A-fragments ----
    bf16x8 a[4];
#pragma unroll
    for (int kc = 0; kc < 4; ++kc) {
        const f4 lo = p.xv[2*kc], hi = p.xv[2*kc+1];
        bf16x8 t;
        t[0]=(short)f2bf(lo[0]); t[1]=(short)f2bf(lo[1]); t[2]=(short)f2bf(lo[2]); t[3]=(short)f2bf(lo[3]);
        t[4]=(short)f2bf(hi[0]); t[5]=(short)f2bf(hi[1]); t[6]=(short)f2bf(hi[2]); t[7]=(short)f2bf(hi[3]);
        a[kc] = t;
    }

    // ---- layer 1: H = X @ W1 — frag-layout LDS reads (conflict-free) ----
    f32x4 acc1[8];
#pragma unroll
    for (int ct = 0; ct < 8; ++ct) acc1[ct] = zero;
#pragma unroll
    for (int kc = 0; kc < 4; ++kc) {
#pragma unroll
        for (int ct = 0; ct < 8; ++ct) {
            const bf16x8 b = *(const bf16x8*)&w1f[(kc*8 + ct)*512 + l*8];
            acc1[ct] = __builtin_amdgcn_mfma_f32_16x16x32_bf16(a[kc], b, acc1[ct], 0, 0, 0);
        }
    }

    // ---- bias + silu -> h to per-wave LDS (swizzled, true-column layout) ----
#pragma unroll
    for (int hh = 0; hh < 2; ++hh) {
#pragma unroll
        for (int r = 0; r < 4; ++r) {
            const int row = g*4 + r;
            float z0 = acc1[hh*4+0][r] + b1f[hh*4+0];
            float z1 = acc1[hh*4+1][r] + b1f[hh*4+1];
            float z2 = acc1[hh*4+2][r] + b1f[hh*4+2];
            float z3 = acc1[hh*4+3][r] + b1f[hh*4+3];
            ushort4 pk;
            pk.x = f2bf(z0 / (1.f + __expf(-z0)));
            pk.y = f2bf(z1 / (1.f + __expf(-z1)));
            pk.z = f2bf(z2 / (1.f + __expf(-z2)));
            pk.w = f2bf(z3 / (1.f + __expf(-z3)));
            const int c0  = hh*64 + 4*ln;
            const int idx = row*128 + (((c0 >> 3) ^ (row & 7)) << 3) + (c0 & 7);
            *(ushort4*)&hw[idx] = pk;
        }
    }

    // ---- read h A-fragments (same-wave LDS round trip, no barrier) ----
    bf16x8 ha[4];
#pragma unroll
    for (int kc = 0; kc < 4; ++kc) {
        const int u = kc*4 + g;
        ha[kc] = *(const bf16x8*)&hw[ln*128 + ((u ^ (ln & 7)) << 3)];
    }

    // ---- layer 2: Y = H @ W2 — frag-layout LDS reads ----
    f32x4 acc2[8];
#pragma unroll
    for (int ct = 0; ct < 8; ++ct) acc2[ct] = zero;
#pragma unroll
    for (int kc = 0; kc < 4; ++kc) {
#pragma unroll
        for (int ct = 0; ct < 8; ++ct) {
            const bf16x8 b = *(const bf16x8*)&w2f[(kc*8 + ct)*512 + l*8];
            acc2[ct] = __builtin_amdgcn_mfma_f32_16x16x32_bf16(ha[kc], b, acc2[ct], 0, 0, 0);
        }
    }

    // ---- DIRECT epilogue: bias + mask/decay, nt f4 stores straight from acc2.
    //      Permuted cols make acc2[hh*4+0..3][r] = cols hh*64+4*ln..+3 of row g*4+r:
    //      per instruction 4 rows x 256B contiguous — sector-complete; nt avoids
    //      the write-allocate path that inflated WRITE pre-v10. ----
#pragma unroll
    for (int r = 0; r < 4; ++r) {
        const int row = g*4 + r;
        float* op = out + (long)(row0 + row) * D_DIM + 4*ln;
#pragma unroll
        for (int hh = 0; hh < 2; ++hh) {
            f4 f;
            f[0] = (acc2[hh*4+0][r] + b2f[hh*4+0]) * p.mfac[r];
            f[1] = (acc2[hh*4+1][r] + b2f[hh*4+1]) * p.mfac[r];
            f[2] = (acc2[hh*4+2][r] + b2f[hh*4+2]) * p.mfac[r];
            f[3] = (acc2[hh*4+3][r] + b2f[hh*4+3]) * p.mfac[r];
            __builtin_nontemporal_store(f, (f4*)(op + hh*64));
        }
    }
}

__global__ void __launch_bounds__(256, 2)
ssm_fused_v18(const float* __restrict__ x,
              const int*   __restrict__ mask,
              const float* __restrict__ W1,
              const float* __restrict__ b1,
              const float* __restrict__ W2,
              const float* __restrict__ b2,
              float* __restrict__ out) {
    // LDS: weight frags (64 KiB) + h (16 KiB) = 80 KiB -> 2 blocks/CU
    __shared__ __align__(16) u16 wlds[2*16384];
    __shared__ __align__(16) u16 hlds[4*16*128];

    const int tid = threadIdx.x;
    const int l   = tid & 63;
    const int ln  = tid & 15;
    const int g   = (tid >> 4) & 3;
    const int wv  = tid >> 6;

    // ---- stage W1,W2 as bf16 directly in MFMA FRAG LAYOUT (fused prep) ----
    for (int i = tid; i < 4096; i += 256) {
        int k  = i >> 5;
        int n0 = (i & 31) * 4;
        float4 v1 = *(const float4*)(W1 + k*128 + n0);
        float4 v2 = *(const float4*)(W2 + k*128 + n0);
        const float* p1 = (const float*)&v1;
        const float* p2 = (const float*)&v2;
        const int kc = k >> 5;
        const int gg = (k >> 3) & 3;
        const int j  = k & 7;
#pragma unroll
        for (int jj = 0; jj < 4; ++jj) {
            const int col = n0 + jj;
            const int ct  = ((col >> 6) << 2) + (col & 3);
            const int lnn = (col & 63) >> 2;
            const int idx = (kc*8 + ct)*512 + (gg*16 + lnn)*8 + j;
            wlds[idx]         = f2bf(p1[jj]);
            wlds[16384 + idx] = f2bf(p2[jj]);
        }
    }
    __syncthreads();

    const u16* w1f = wlds;            // frag f at u16 offset f*512 + l*8
    const u16* w2f = wlds + 16384;

    // per-lane bias fragments at permuted columns
    float b1f[8], b2f[8];
#pragma unroll
    for (int ct = 0; ct < 8; ++ct) {
        const int col = (ct >> 2)*64 + (ct & 3) + 4*ln;
        b1f[ct] = b1[col];
        b2f[ct] = b2[col];
    }

    u16* hw = hlds + wv * 2048;

    // ---- software-pipelined main loop (ping-pong Pre, pinned issue points) ----
    Pre pa, pb;
    prefetch_issue(x, mask, blockIdx.x, wv, ln, g, pa);
    __builtin_amdgcn_sched_barrier(0);

#pragma unroll 1
    for (int itp = 0; itp < ITERS/2; ++itp) {
        const int tA = blockIdx.x + (2*itp) * NBLK;
        const int tB = tA + NBLK;
        int tC = tB + NBLK; if (tC >= NTILES) tC = tB;

        prefetch_issue(x, mask, tB, wv, ln, g, pb);
        __builtin_amdgcn_sched_barrier(0);
        compute_tile(tA, pa, w1f, w2f, hw, b1f, b2f, out, wv, l, ln, g);

        prefetch_issue(x, mask, tC, wv, ln, g, pa);
        __builtin_amdgcn_sched_barrier(0);
        compute_tile(tB, pb, w1f, w2f, hw, b1f, b2f, out, wv, l, ln, g);
    }
}

extern "C" void kernel_launch(void* const* d_in, const int* in_sizes, int n_in,
                              void* d_out, int out_size, void* d_ws, size_t ws_size,
                              hipStream_t stream) {
    const float* x    = (const float*)d_in[0];
    const int*   mask = (const int*)d_in[1];
    const float* W1   = (const float*)d_in[2];
    const float* b1   = (const float*)d_in[3];
    const float* W2   = (const float*)d_in[4];
    const float* b2   = (const float*)d_in[5];
    float* out = (float*)d_out;

    hipLaunchKernelGGL(ssm_fused_v18, dim3(NBLK), dim3(256), 0, stream,
                       x, mask, W1, b1, W2, b2, out);
}